// Round 1
// baseline (38.080 us; speedup 1.0000x reference)
//
#include <hip/hip_runtime.h>
#include <hip/hip_bf16.h>

typedef __bf16 bf16x8 __attribute__((ext_vector_type(8)));
typedef float f32x4 __attribute__((ext_vector_type(4)));

#define K_DIM 1024
#define N_DIM 128

// ---------------------------------------------------------------------------
// Kernel 1: T(4096x128, bf16) = batch(4096x1024, f32) @ B(1024x128, f32)
// BM=16 rows/block, full N=128, BK=64. 512 threads = 8 waves, wave w owns
// n-tile w (16 cols). LDS holds operand tiles pre-swizzled into MFMA fragment
// order so each operand load is a single ds_read_b128.
// mfma_f32_16x16x32_bf16 operand layout (two chained x16 halves):
//   A/B: 16-dim index = lane%16 ; k = 4*(lane/16) + (i%4) + 16*(i/4), i=0..7
//   D  : col = lane%16 ; row = 4*(lane/16) + i            [verified m89]
// ---------------------------------------------------------------------------
__global__ __launch_bounds__(512)
void proj_kernel(const float* __restrict__ batch, const float* __restrict__ Bmat,
                 unsigned short* __restrict__ T) {
  __shared__ __align__(16) unsigned short As[2 * 64 * 8];      // [ks][lane][8]
  __shared__ __align__(16) unsigned short Bs[8 * 2 * 64 * 8];  // [nt][ks][lane][8]

  const int t  = threadIdx.x;
  const int m0 = blockIdx.x * 16;
  const int w  = t >> 6;   // wave id = n-tile
  const int l  = t & 63;

  const int am  = t >> 5;         // A row 0..15 (2 waves per row-group)
  const int akk = (t & 31) * 2;   // A col pair base 0..62

  f32x4 acc = {0.f, 0.f, 0.f, 0.f};
  float2 aReg;
  float2 bReg[8];

  auto ld = [&](int k0) {
    aReg = *(const float2*)(batch + (size_t)(m0 + am) * K_DIM + k0 + akk);
#pragma unroll
    for (int j = 0; j < 8; ++j) {
      int idx = j * 512 + t;
      int kk  = idx >> 6;          // 0..63
      int n   = (idx & 63) * 2;    // 0..126
      bReg[j] = *(const float2*)(Bmat + (size_t)(k0 + kk) * N_DIM + n);
    }
  };

  auto st = [&]() {
    // A tile -> swizzled fragments
#pragma unroll
    for (int e = 0; e < 2; ++e) {
      int kk = akk + e;
      int ks = kk >> 5, kr = kk & 31;
      int lane = am + 16 * ((kr & 15) >> 2);
      int el   = (kr & 3) + 4 * (kr >> 4);
      float v  = e ? aReg.y : aReg.x;
      __hip_bfloat16 h = __float2bfloat16(v);
      As[(ks * 64 + lane) * 8 + el] = *(unsigned short*)&h;
    }
    // B tile -> swizzled fragments
#pragma unroll
    for (int j = 0; j < 8; ++j) {
      int idx = j * 512 + t;
      int kk  = idx >> 6;
      int nb  = (idx & 63) * 2;
      int ks  = kk >> 5, kr = kk & 31;
      int el  = (kr & 3) + 4 * (kr >> 4);
      int g16 = 16 * ((kr & 15) >> 2);
#pragma unroll
      for (int e = 0; e < 2; ++e) {
        int n    = nb + e;
        int nt   = n >> 4;
        int lane = (n & 15) + g16;
        float v  = e ? bReg[j].y : bReg[j].x;
        __hip_bfloat16 h = __float2bfloat16(v);
        Bs[((nt * 2 + ks) * 64 + lane) * 8 + el] = *(unsigned short*)&h;
      }
    }
  };

  ld(0);
  st();
  __syncthreads();

  for (int it = 0; it < 16; ++it) {
    if (it < 15) ld((it + 1) * 64);  // prefetch next tile into regs
#pragma unroll
    for (int ks = 0; ks < 2; ++ks) {
      bf16x8 a = *(const bf16x8*)&As[(ks * 64 + l) * 8];
      bf16x8 b = *(const bf16x8*)&Bs[((w * 2 + ks) * 64 + l) * 8];
      acc = __builtin_amdgcn_mfma_f32_16x16x32_bf16(a, b, acc, 0, 0, 0);
    }
    __syncthreads();                 // all frag reads done
    if (it < 15) {
      st();                          // write prefetched tile
      __syncthreads();
    }
  }

  // epilogue: D frag -> T (bf16)
  const int row = m0 + 4 * (l >> 4);
  const int col = w * 16 + (l & 15);
#pragma unroll
  for (int i = 0; i < 4; ++i) {
    __hip_bfloat16 h = __float2bfloat16(acc[i]);
    T[(size_t)(row + i) * N_DIM + col] = *(unsigned short*)&h;
  }
}

// ---------------------------------------------------------------------------
// Kernel 2: per batch b, out[i,j] = n_i + n_j - 2 * (T_i . T_j)
// grid = 16 batches * 16 tiles (64x64). 256 threads = 4 waves, wave w owns a
// 32x32 quadrant (2x2 MFMA tiles). Ti/Tj staged once in fragment-swizzled LDS
// (K=128 = 4 k-steps). Row norms computed during staging via shfl-16 reduce.
// ---------------------------------------------------------------------------
__global__ __launch_bounds__(256)
void dist_kernel(const unsigned short* __restrict__ T, float* __restrict__ out) {
  const int bb   = blockIdx.x >> 4;
  const int tile = blockIdx.x & 15;
  const int i0   = (tile >> 2) * 64;
  const int j0   = (tile & 3) * 64;
  const int t    = threadIdx.x;

  __shared__ __align__(16) unsigned short TiS[16 * 64 * 8];  // [mt*4+ks][lane][8]
  __shared__ __align__(16) unsigned short TjS[16 * 64 * 8];
  __shared__ float ni[64];
  __shared__ float nj[64];

  const size_t rowBase = (size_t)bb * 256;

  auto stage = [&](int off, unsigned short* S, float* nrm) {
#pragma unroll
    for (int jr = 0; jr < 4; ++jr) {
      int idx = jr * 256 + t;
      int r   = idx >> 4;   // row 0..63
      int c8  = idx & 15;   // 8-col chunk
      const uint4 u = *(const uint4*)(T + (rowBase + off + r) * 128 + c8 * 8);
      unsigned ux[4] = {u.x, u.y, u.z, u.w};
      float psum = 0.f;
      int mt = r >> 4, m = r & 15;
#pragma unroll
      for (int q = 0; q < 4; ++q) {
#pragma unroll
        for (int h = 0; h < 2; ++h) {
          unsigned short raw = h ? (unsigned short)(ux[q] >> 16)
                                 : (unsigned short)(ux[q] & 0xffffu);
          float v = __uint_as_float((unsigned)raw << 16);
          psum += v * v;
          int kk = c8 * 8 + q * 2 + h;
          int ks = kk >> 5, kr = kk & 31;
          int lane = m + 16 * ((kr & 15) >> 2);
          int el   = (kr & 3) + 4 * (kr >> 4);
          S[((mt * 4 + ks) * 64 + lane) * 8 + el] = raw;
        }
      }
      float s = psum;
      s += __shfl_xor(s, 1);
      s += __shfl_xor(s, 2);
      s += __shfl_xor(s, 4);
      s += __shfl_xor(s, 8);
      if ((t & 15) == 0) nrm[r] = s;
    }
  };

  stage(i0, TiS, ni);
  stage(j0, TjS, nj);
  __syncthreads();

  const int w = t >> 6, l = t & 63;
  const int wi = w >> 1, wj = w & 1;

  f32x4 acc[2][2] = {{{0.f,0.f,0.f,0.f}, {0.f,0.f,0.f,0.f}},
                     {{0.f,0.f,0.f,0.f}, {0.f,0.f,0.f,0.f}}};
#pragma unroll
  for (int ks = 0; ks < 4; ++ks) {
    bf16x8 a[2], b[2];
#pragma unroll
    for (int d = 0; d < 2; ++d) {
      a[d] = *(const bf16x8*)&TiS[(((2 * wi + d) * 4 + ks) * 64 + l) * 8];
      b[d] = *(const bf16x8*)&TjS[(((2 * wj + d) * 4 + ks) * 64 + l) * 8];
    }
#pragma unroll
    for (int di = 0; di < 2; ++di)
#pragma unroll
      for (int dj = 0; dj < 2; ++dj)
        acc[di][dj] = __builtin_amdgcn_mfma_f32_16x16x32_bf16(a[di], b[dj], acc[di][dj], 0, 0, 0);
  }

#pragma unroll
  for (int di = 0; di < 2; ++di)
#pragma unroll
    for (int dj = 0; dj < 2; ++dj) {
      int li = (2 * wi + di) * 16 + 4 * (l >> 4);
      int lj = (2 * wj + dj) * 16 + (l & 15);
#pragma unroll
      for (int i = 0; i < 4; ++i) {
        float v = ni[li + i] + nj[lj] - 2.0f * acc[di][dj][i];
        out[(rowBase + i0 + li + i) * 256 + (j0 + lj)] = v;
      }
    }
}

extern "C" void kernel_launch(void* const* d_in, const int* in_sizes, int n_in,
                              void* d_out, int out_size, void* d_ws, size_t ws_size,
                              hipStream_t stream) {
  const float* batch = (const float*)d_in[0];   // (16,256,1024) f32
  const float* Bmat  = (const float*)d_in[1];   // (1024,128) f32
  unsigned short* T  = (unsigned short*)d_ws;   // 4096x128 bf16 = 1 MB
  float* out         = (float*)d_out;           // (16,256,256) f32

  proj_kernel<<<256, 512, 0, stream>>>(batch, Bmat, T);
  dist_kernel<<<256, 256, 0, stream>>>(T, out);
}

// Round 2
// 31.254 us; speedup vs baseline: 1.2184x; 1.2184x over previous
//
#include <hip/hip_runtime.h>
#include <hip/hip_bf16.h>

typedef __bf16 bf16x8 __attribute__((ext_vector_type(8)));
typedef float f32x4 __attribute__((ext_vector_type(4)));

#define K_DIM 1024
#define N_DIM 128

// ws layout:
//   [0, 256KB)        Bfrag: [w:8][ks:32][lane:64][elem:8] bf16
//   [256KB, +1MB)     Tfrag: [rg:256][ks:4][lane:64][elem:8] bf16
//   [256KB+1MB, +16K) nrm:   [4096] f32  (row squared norms of rounded T)
//
// Fragment convention (validated in R0, mfma_f32_16x16x32_bf16):
//   operand (A or B): 16-idx = lane%16, k = 4*(lane/16) + (e&3) + 16*(e>>2)
//   D: col = lane&15, row = 4*(lane>>4) + i
// K1 computes mfma(X=B^T-frag, Y=A-frag) so D elems land exactly in the
// fragment layout K2 consumes (col=batch-row, row-of-D = T-col).

__device__ inline unsigned pk2(float x, float y) {
  __hip_bfloat16 hx = __float2bfloat16(x), hy = __float2bfloat16(y);
  return (unsigned)*(unsigned short*)&hx | ((unsigned)*(unsigned short*)&hy << 16);
}

// ---------------------------------------------------------------------------
// prep: B (1024x128 f32) -> Bfrag bf16 fragments. 64 blocks x 256 thr.
// Wave W = (w = W>>5, ks = W&31). elem e: k = 32ks + 4*(l>>4) + (e&3) + 16*(e>>2)
// ---------------------------------------------------------------------------
__global__ __launch_bounds__(256)
void prep_kernel(const float* __restrict__ B, unsigned short* __restrict__ Bfrag) {
  const int t = threadIdx.x;
  const int W = blockIdx.x * 4 + (t >> 6);  // 0..255
  const int w = W >> 5, ks = W & 31, l = t & 63;
  const int col = 16 * w + (l & 15);
  const int kb = 32 * ks + 4 * (l >> 4);
  unsigned u[4];
#pragma unroll
  for (int j = 0; j < 4; ++j) {
    int k0 = kb + 2 * (j & 1) + 16 * (j >> 1);
    u[j] = pk2(B[(size_t)k0 * N_DIM + col], B[(size_t)(k0 + 1) * N_DIM + col]);
  }
  *(uint4*)&Bfrag[((size_t)(w * 32 + ks) * 64 + l) * 8] =
      make_uint4(u[0], u[1], u[2], u[3]);
}

// ---------------------------------------------------------------------------
// K1: T = batch @ B, emitted directly as K2 fragments + row norms.
// 256 blocks x 512 thr. Block = one 16-row group; wave w = col chunk 16w.
// Zero-barrier main loop: per k-step 2x dwordx4 A + 1x dwordx4 Bfrag + 1 MFMA.
// ---------------------------------------------------------------------------
__global__ __launch_bounds__(512)
void proj_kernel(const float* __restrict__ batch,
                 const unsigned short* __restrict__ Bfrag,
                 unsigned short* __restrict__ Tfrag,
                 float* __restrict__ nrm) {
  __shared__ float part[8][16];
  const int t = threadIdx.x, w = t >> 6, l = t & 63;
  const int m0 = blockIdx.x * 16;
  const int row = m0 + (l & 15);

  const float* aptr = batch + (size_t)row * K_DIM + 4 * (l >> 4);
  const unsigned short* bptr = Bfrag + ((size_t)w * 32 * 64 + l) * 8;

  f32x4 acc = {0.f, 0.f, 0.f, 0.f};
#pragma unroll 4
  for (int ks = 0; ks < 32; ++ks) {
    f32x4 a0 = *(const f32x4*)(aptr + ks * 32);
    f32x4 a1 = *(const f32x4*)(aptr + ks * 32 + 16);
    bf16x8 bf = *(const bf16x8*)(bptr + (size_t)ks * 64 * 8);
    uint4 uu = make_uint4(pk2(a0.x, a0.y), pk2(a0.z, a0.w),
                          pk2(a1.x, a1.y), pk2(a1.z, a1.w));
    bf16x8 af = *(bf16x8*)&uu;
    acc = __builtin_amdgcn_mfma_f32_16x16x32_bf16(bf, af, acc, 0, 0, 0);
  }

  // Store T fragment: wave w covers T cols 16w + 4*(l>>4) + {0..3} of row (l&15).
  // -> frag[rg=blockIdx][ks=w>>1][lane=l][elems 4*(w&1)..+3]
  unsigned lo = pk2(acc[0], acc[1]);
  unsigned hi = pk2(acc[2], acc[3]);
  *(uint2*)&Tfrag[(((size_t)blockIdx.x * 4 + (w >> 1)) * 64 + l) * 8 + (w & 1) * 4] =
      make_uint2(lo, hi);

  // Row norms from the ROUNDED values (consistency with K2's Gram).
  float v0 = __uint_as_float(lo << 16);
  float v1 = __uint_as_float(lo & 0xffff0000u);
  float v2 = __uint_as_float(hi << 16);
  float v3 = __uint_as_float(hi & 0xffff0000u);
  float s = v0 * v0 + v1 * v1 + v2 * v2 + v3 * v3;  // partial: 4 cols of row l&15
  s += __shfl_xor(s, 16);
  s += __shfl_xor(s, 32);   // now: sum over this wave's 16 cols
  if (l < 16) part[w][l] = s;
  __syncthreads();
  if (t < 16) {
    float n = 0.f;
#pragma unroll
    for (int ww = 0; ww < 8; ++ww) n += part[ww][t];  // fixed order: deterministic
    nrm[m0 + t] = n;
  }
}

// ---------------------------------------------------------------------------
// K2: out[b,i,j] = n_i + n_j - 2 * (T_i . T_j). 256 blocks x 256 thr,
// wave-independent (no LDS, no barriers). Wave = one 32x32 output tile.
// ---------------------------------------------------------------------------
__global__ __launch_bounds__(256)
void dist_kernel(const unsigned short* __restrict__ Tfrag,
                 const float* __restrict__ nrm, float* __restrict__ out) {
  const int t = threadIdx.x, l = t & 63;
  const int W = blockIdx.x * 4 + (t >> 6);  // 0..1023
  const int bb = W >> 6, tile = W & 63;
  const int ti = (tile >> 3) * 32, tj = (tile & 7) * 32;
  const int rbase = bb * 256;

  bf16x8 ifr[2][4], jfr[2][4];
#pragma unroll
  for (int d = 0; d < 2; ++d)
#pragma unroll
    for (int ks = 0; ks < 4; ++ks) {
      ifr[d][ks] = *(const bf16x8*)
          &Tfrag[((((size_t)bb * 16 + (ti >> 4) + d) * 4 + ks) * 64 + l) * 8];
      jfr[d][ks] = *(const bf16x8*)
          &Tfrag[((((size_t)bb * 16 + (tj >> 4) + d) * 4 + ks) * 64 + l) * 8];
    }

  f32x4 acc[2][2] = {{{0.f,0.f,0.f,0.f}, {0.f,0.f,0.f,0.f}},
                     {{0.f,0.f,0.f,0.f}, {0.f,0.f,0.f,0.f}}};
#pragma unroll
  for (int ks = 0; ks < 4; ++ks)
#pragma unroll
    for (int di = 0; di < 2; ++di)
#pragma unroll
      for (int dj = 0; dj < 2; ++dj)
        acc[di][dj] = __builtin_amdgcn_mfma_f32_16x16x32_bf16(
            ifr[di][ks], jfr[dj][ks], acc[di][dj], 0, 0, 0);

#pragma unroll
  for (int di = 0; di < 2; ++di) {
    const f32x4 ni = *(const f32x4*)&nrm[rbase + ti + 16 * di + 4 * (l >> 4)];
#pragma unroll
    for (int dj = 0; dj < 2; ++dj) {
      const float njv = nrm[rbase + tj + 16 * dj + (l & 15)];
#pragma unroll
      for (int ii = 0; ii < 4; ++ii) {
        out[(size_t)(rbase + ti + 16 * di + 4 * (l >> 4) + ii) * 256
            + tj + 16 * dj + (l & 15)] = ni[ii] + njv - 2.f * acc[di][dj][ii];
      }
    }
  }
}

extern "C" void kernel_launch(void* const* d_in, const int* in_sizes, int n_in,
                              void* d_out, int out_size, void* d_ws, size_t ws_size,
                              hipStream_t stream) {
  const float* batch = (const float*)d_in[0];  // (16,256,1024) f32
  const float* Bmat  = (const float*)d_in[1];  // (1024,128) f32
  unsigned short* Bfrag = (unsigned short*)d_ws;              // 256 KB
  unsigned short* Tfrag = Bfrag + 8 * 32 * 64 * 8;            // 1 MB
  float* nrm = (float*)(Tfrag + 256 * 4 * 64 * 8);            // 16 KB
  float* out = (float*)d_out;                                 // (16,256,256) f32

  prep_kernel<<<64, 256, 0, stream>>>(Bmat, Bfrag);
  proj_kernel<<<256, 512, 0, stream>>>(batch, Bfrag, Tfrag, nrm);
  dist_kernel<<<256, 256, 0, stream>>>(Tfrag, nrm, out);
}

// Round 3
// 20.918 us; speedup vs baseline: 1.8205x; 1.4941x over previous
//
#include <hip/hip_runtime.h>
#include <hip/hip_bf16.h>

typedef __bf16 bf16x8 __attribute__((ext_vector_type(8)));
typedef float f32x4 __attribute__((ext_vector_type(4)));

#define K_DIM 1024
#define N_DIM 128

// ws layout:
//   [0, 256KB)        Bfrag: [w:8][ks:32][lane:64][elem:8] bf16
//   [256KB, +1MB)     Tfrag: [rg:256][ks:4][lane:64][elem:8] bf16
//   [256KB+1MB, +16K) nrm:   [4096] f32
//
// Fragment convention (validated R0/R2, mfma_f32_16x16x32_bf16):
//   operand: 16-idx = lane%16, k = 4*(lane/16) + (e&3) + 16*(e>>2)
//   D: col = lane&15 (= operand2's 16-idx), row = 4*(lane>>4)+i (= operand1's)

__device__ inline unsigned pk2(float x, float y) {
  __hip_bfloat16 hx = __float2bfloat16(x), hy = __float2bfloat16(y);
  return (unsigned)*(unsigned short*)&hx | ((unsigned)*(unsigned short*)&hy << 16);
}

// ---------------------------------------------------------------------------
// prep: B (1024x128 f32) -> Bfrag. 256 blocks x 64 thr (1 wave each, min
// latency). Wave W = (w=W>>5, ks=W&31); elem e: k = 32ks+4*(l>>4)+(e&3)+16*(e>>2)
// ---------------------------------------------------------------------------
__global__ __launch_bounds__(64)
void prep_kernel(const float* __restrict__ B, unsigned short* __restrict__ Bfrag) {
  const int W = blockIdx.x, l = threadIdx.x;
  const int w = W >> 5, ks = W & 31;
  const int col = 16 * w + (l & 15);
  const int kb = 32 * ks + 4 * (l >> 4);
  unsigned u[4];
#pragma unroll
  for (int j = 0; j < 4; ++j) {
    int k0 = kb + 2 * (j & 1) + 16 * (j >> 1);
    u[j] = pk2(B[(size_t)k0 * N_DIM + col], B[(size_t)(k0 + 1) * N_DIM + col]);
  }
  *(uint4*)&Bfrag[((size_t)(w * 32 + ks) * 64 + l) * 8] =
      make_uint4(u[0], u[1], u[2], u[3]);
}

// ---------------------------------------------------------------------------
// K1: T = batch @ B. 256 blocks x 512 thr. Block = 16 rows (64 KB of batch,
// linearly contiguous). Stage A once into LDS in fragment layout (bf16,
// XOR-swizzled), then 32 k-steps of ds_read_b128 + Bfrag dwordx4 + MFMA.
// ---------------------------------------------------------------------------
__global__ __launch_bounds__(512)
void proj_kernel(const float* __restrict__ batch,
                 const unsigned short* __restrict__ Bfrag,
                 unsigned short* __restrict__ Tfrag,
                 float* __restrict__ nrm) {
  __shared__ __align__(16) unsigned short Asl[32 * 64 * 8];  // 32 KB
  __shared__ float part[8][16];
  const int t = threadIdx.x, w = t >> 6, l = t & 63;
  const int m0 = blockIdx.x * 16;

  // ---- stage A: linear 64 KB -> bf16 fragments (coalesced 1KB/instr) ----
  const float* src = batch + (size_t)m0 * K_DIM;
#pragma unroll
  for (int j = 0; j < 8; ++j) {
    int fidx = j * 512 + t;                       // f32x4 chunk index
    f32x4 v = *(const f32x4*)(src + 4 * (size_t)fidx);
    int r = fidx >> 8;                            // block row 0..15
    int q = fidx & 255;                           // k-quad within row
    int ks = q >> 3, qq = q & 7, g = qq & 3, h = qq >> 2;
    unsigned lo = pk2(v.x, v.y), hi = pk2(v.z, v.w);
    int byte = ks * 1024 + ((16 * (r + 16 * g)) ^ ((ks & 7) << 4)) + 8 * h;
    *(uint2*)((char*)Asl + byte) = make_uint2(lo, hi);
  }
  __syncthreads();

  // ---- k-loop: zero barriers, static LDS offsets ----
  const unsigned short* bptr = Bfrag + ((size_t)w * 32 * 64 + l) * 8;
  f32x4 acc0 = {0.f, 0.f, 0.f, 0.f}, acc1 = {0.f, 0.f, 0.f, 0.f};
#pragma unroll
  for (int ks = 0; ks < 32; ks += 2) {
    bf16x8 a0 = *(const bf16x8*)((const char*)Asl +
                   (ks * 1024 + ((l * 16) ^ ((ks & 7) << 4))));
    bf16x8 b0 = *(const bf16x8*)(bptr + (size_t)ks * 512);
    acc0 = __builtin_amdgcn_mfma_f32_16x16x32_bf16(b0, a0, acc0, 0, 0, 0);
    bf16x8 a1 = *(const bf16x8*)((const char*)Asl +
                   ((ks + 1) * 1024 + ((l * 16) ^ (((ks + 1) & 7) << 4))));
    bf16x8 b1 = *(const bf16x8*)(bptr + (size_t)(ks + 1) * 512);
    acc1 = __builtin_amdgcn_mfma_f32_16x16x32_bf16(b1, a1, acc1, 0, 0, 0);
  }
  f32x4 acc = acc0 + acc1;

  // ---- store T fragment (validated layout) + row norms ----
  unsigned lo = pk2(acc[0], acc[1]);
  unsigned hi = pk2(acc[2], acc[3]);
  *(uint2*)&Tfrag[(((size_t)blockIdx.x * 4 + (w >> 1)) * 64 + l) * 8 + (w & 1) * 4] =
      make_uint2(lo, hi);

  float v0 = __uint_as_float(lo << 16);
  float v1 = __uint_as_float(lo & 0xffff0000u);
  float v2 = __uint_as_float(hi << 16);
  float v3 = __uint_as_float(hi & 0xffff0000u);
  float s = v0 * v0 + v1 * v1 + v2 * v2 + v3 * v3;
  s += __shfl_xor(s, 16);
  s += __shfl_xor(s, 32);           // sum over this wave's 16 cols of row l&15
  if (l < 16) part[w][l] = s;
  __syncthreads();
  if (t < 16) {
    float n = 0.f;
#pragma unroll
    for (int ww = 0; ww < 8; ++ww) n += part[ww][t];  // fixed order
    nrm[m0 + t] = n;
  }
}

// ---------------------------------------------------------------------------
// K2: out[b,i,j] = n_i + n_j - 2*(T_i.T_j). 512 blocks x 256 thr (2048 waves,
// 2/SIMD). Wave = 32x16 output tile: 12 frag loads, 8 MFMA, no LDS/barriers.
// ---------------------------------------------------------------------------
__global__ __launch_bounds__(256)
void dist_kernel(const unsigned short* __restrict__ Tfrag,
                 const float* __restrict__ nrm, float* __restrict__ out) {
  const int t = threadIdx.x, l = t & 63;
  const int W = blockIdx.x * 4 + (t >> 6);  // 0..2047
  const int bb = W >> 7, tile = W & 127;
  const int ti = (tile >> 4) * 32, tj = (tile & 15) * 16;
  const int rbase = bb * 256;

  bf16x8 ifr[2][4], jfr[4];
#pragma unroll
  for (int ks = 0; ks < 4; ++ks) {
    jfr[ks] = *(const bf16x8*)
        &Tfrag[((((size_t)bb * 16 + (tj >> 4)) * 4 + ks) * 64 + l) * 8];
#pragma unroll
    for (int d = 0; d < 2; ++d)
      ifr[d][ks] = *(const bf16x8*)
          &Tfrag[((((size_t)bb * 16 + (ti >> 4) + d) * 4 + ks) * 64 + l) * 8];
  }

  f32x4 acc[2] = {{0.f,0.f,0.f,0.f}, {0.f,0.f,0.f,0.f}};
#pragma unroll
  for (int ks = 0; ks < 4; ++ks)
#pragma unroll
    for (int di = 0; di < 2; ++di)
      acc[di] = __builtin_amdgcn_mfma_f32_16x16x32_bf16(
          ifr[di][ks], jfr[ks], acc[di], 0, 0, 0);

  const float njv = nrm[rbase + tj + (l & 15)];
#pragma unroll
  for (int di = 0; di < 2; ++di) {
    const f32x4 ni = *(const f32x4*)&nrm[rbase + ti + 16 * di + 4 * (l >> 4)];
#pragma unroll
    for (int ii = 0; ii < 4; ++ii) {
      out[(size_t)(rbase + ti + 16 * di + 4 * (l >> 4) + ii) * 256
          + tj + (l & 15)] = ni[ii] + njv - 2.f * acc[di][ii];
    }
  }
}

extern "C" void kernel_launch(void* const* d_in, const int* in_sizes, int n_in,
                              void* d_out, int out_size, void* d_ws, size_t ws_size,
                              hipStream_t stream) {
  const float* batch = (const float*)d_in[0];  // (16,256,1024) f32
  const float* Bmat  = (const float*)d_in[1];  // (1024,128) f32
  unsigned short* Bfrag = (unsigned short*)d_ws;              // 256 KB
  unsigned short* Tfrag = Bfrag + 8 * 32 * 64 * 8;            // 1 MB
  float* nrm = (float*)(Tfrag + 256 * 4 * 64 * 8);            // 16 KB
  float* out = (float*)d_out;                                 // (16,256,256) f32

  prep_kernel<<<256, 64, 0, stream>>>(Bmat, Bfrag);
  proj_kernel<<<256, 512, 0, stream>>>(batch, Bfrag, Tfrag, nrm);
  dist_kernel<<<512, 256, 0, stream>>>(Tfrag, nrm, out);
}